// Round 7
// baseline (596.072 us; speedup 1.0000x reference)
//
#include <hip/hip_runtime.h>

// Problem constants (fixed by setup_inputs)
#define NNODES 8000
#define NEDGES 192000
#define NREL   65
#define RP     66      // +1 pseudo-relation for the root/self term
#define HDIM   256
#define FDIM   64
#define NGRAPH 128
#define MDIM   64
#define TILE_M 64
#define MAXT   3456    // >= E/64 + RP + N/64 = 3190; == 8*432 == 9*384 for swizzles
#define EPTOT  (NEDGES + NNODES)

typedef _Float16 half8 __attribute__((ext_vector_type(8)));
typedef _Float16 half4 __attribute__((ext_vector_type(4)));
typedef float    f32x4 __attribute__((ext_vector_type(4)));
// clang vector type (NOT HIP's struct uint4) — required by __builtin_nontemporal_*
typedef unsigned int u32x4 __attribute__((ext_vector_type(4)));

// ---------------- setup kernels ----------------

__global__ void count_kernel(const int* __restrict__ ei, const int* __restrict__ et,
                             int* __restrict__ cnt_rn, int* __restrict__ type_cnt,
                             int* __restrict__ ddeg) {
    __shared__ int lbin[NREL];
    int tid = threadIdx.x;
    if (tid < NREL) lbin[tid] = 0;
    __syncthreads();
    int e = blockIdx.x * 256 + tid;
    if (e < NEDGES) {
        int t = et[e];
        int d = ei[NEDGES + e];
        atomicAdd(&lbin[t], 1);
        atomicAdd(&cnt_rn[t * NNODES + d], 1);
        atomicAdd(&ddeg[d], 1);
    }
    __syncthreads();
    if (tid < NREL && lbin[tid] > 0) atomicAdd(&type_cnt[tid], lbin[tid]);
}

__global__ void scan_tiles_kernel(const int* __restrict__ type_cnt, int* __restrict__ type_off,
                                  int* __restrict__ tile_rel, int* __restrict__ tile_start,
                                  int* __restrict__ tile_nrows) {
    __shared__ int s_off[RP + 1];
    __shared__ int s_toff[RP + 1];
    if (threadIdx.x == 0) {
        int off = 0, toff = 0;
        for (int r = 0; r < RP; r++) {
            int c = (r < NREL) ? type_cnt[r] : NNODES;
            s_off[r] = off; s_toff[r] = toff;
            off += c; toff += (c + TILE_M - 1) / TILE_M;
        }
        s_off[RP] = off; s_toff[RP] = toff;
        type_off[RP] = off;
    }
    __syncthreads();
    int r = threadIdx.x;
    if (r < RP) {
        type_off[r] = s_off[r];
        int c = s_off[r + 1] - s_off[r];
        int nt = (c + TILE_M - 1) / TILE_M;
        for (int i = 0; i < nt; i++) {
            int idx = s_toff[r] + i;
            tile_rel[idx]   = r;
            tile_start[idx] = s_off[r] + i * TILE_M;
            tile_nrows[idx] = min(TILE_M, c - i * TILE_M);
        }
    }
}

// Exclusive prefix scan of (ddeg[n]+1) -> dst_off[0..NNODES]; +1 = root pseudo-edge.
__global__ void dst_scan_kernel(const int* __restrict__ ddeg, int* __restrict__ dst_off) {
    __shared__ int part[256];
    int t = threadIdx.x;
    int base = t * 32;
    int s = 0;
    for (int i = 0; i < 32; i++) {
        int n = base + i;
        if (n < NNODES) s += ddeg[n] + 1;
    }
    part[t] = s;
    __syncthreads();
    if (t == 0) {
        int run = 0;
        for (int i = 0; i < 256; i++) { int tmp = part[i]; part[i] = run; run += tmp; }
        dst_off[NNODES] = run;   // == EPTOT
    }
    __syncthreads();
    int run = part[t];
    for (int i = 0; i < 32; i++) {
        int n = base + i;
        if (n < NNODES) { dst_off[n] = run; run += ddeg[n] + 1; }
    }
}

// Relation-sorted slot p (block-aggregated rank) + dst-sorted output slot q.
__global__ void scatter_kernel(const int* __restrict__ ei, const int* __restrict__ et,
                               const int* __restrict__ cnt_rn, const int* __restrict__ type_off,
                               int* __restrict__ type_cur,
                               const int* __restrict__ dst_off, int* __restrict__ dst_cur,
                               int* __restrict__ esrc, int* __restrict__ eq,
                               float* __restrict__ escale) {
    __shared__ int lbin[NREL];
    __shared__ int gbase[NREL];
    int tid = threadIdx.x;
    if (tid < NREL) lbin[tid] = 0;
    __syncthreads();
    int i = blockIdx.x * 256 + tid;
    int t = 0, lrank = 0;
    bool is_edge = (i < NEDGES);
    if (is_edge) {
        t = et[i];
        lrank = atomicAdd(&lbin[t], 1);
    }
    __syncthreads();
    if (tid < NREL && lbin[tid] > 0) gbase[tid] = atomicAdd(&type_cur[tid], lbin[tid]);
    __syncthreads();
    if (is_edge) {
        int d = ei[NEDGES + i];
        int p = type_off[t] + gbase[t] + lrank;
        int q = dst_off[d] + atomicAdd(&dst_cur[d], 1);
        esrc[p] = ei[i];
        eq[p] = q;
        escale[p] = 1.0f / (float)cnt_rn[t * NNODES + d];
    } else if (i < EPTOT) {
        int n = i - NEDGES;
        int p = NEDGES + n;      // root pseudo-relation segment starts at E
        int q = dst_off[n] + atomicAdd(&dst_cur[n], 1);
        esrc[p] = n; eq[p] = q; escale[p] = 1.0f;
    }
}

// W [R][K][HDIM] fp32 (+ root [K][HDIM]) -> Wt [RP][HDIM][K] fp16 (transposed)
__global__ void convW_kernel(const float* __restrict__ W, const float* __restrict__ root,
                             _Float16* __restrict__ Wt, int K) {
    int r = blockIdx.x, k0 = blockIdx.y * 32, n0 = blockIdx.z * 32;
    const float* src = (r < NREL) ? (W + (size_t)r * K * HDIM) : root;
    __shared__ float tile[32][33];
    int tj = threadIdx.x & 31, ti = threadIdx.x >> 5;
    #pragma unroll
    for (int s = 0; s < 4; s++) {
        int i = ti + s * 8;
        tile[i][tj] = src[(size_t)(k0 + i) * HDIM + n0 + tj];
    }
    __syncthreads();
    #pragma unroll
    for (int s = 0; s < 4; s++) {
        int i = ti + s * 8;
        Wt[((size_t)r * HDIM + (n0 + i)) * K + k0 + tj] = (_Float16)tile[tj][i];
    }
}

__global__ void conv_x_kernel(const float* __restrict__ x, _Float16* __restrict__ x16) {
    int i = blockIdx.x * 256 + threadIdx.x;
    if (i < NNODES * FDIM) x16[i] = (_Float16)x[i];
}

// ---------------- phase 1: Y16[q] = scale * (h[src] @ W_r) ----------------
// Round 7: ROW-SPLIT occupancy isolation (R6 post-mortem: occupancy 70% with
// unchanged time was CONFOUNDED — col-split duplicated A-fetch (FETCH 26->95MB)
// and fragmented writes to 128B (WRITE 100->169MB, RMW amplification). Net
// traffic +136MB ~ +21us cancelled any occupancy gain.)
// This round: 2 blocks per logical tile split by ROWS (32 each):
//  - acc[2][4]=32 accumulators -> fits 8 waves/SIMD (launch_bounds(256,8));
//  - no A duplication: each half gathers its own 32 rows -> FETCH ~26MB;
//  - full 256B row writes -> WRITE ~100MB, no amplification;
//  - LDS ~17.2KB -> 8 blocks/CU.
// Clean A/B: occupancy ~70% at R3's traffic profile. If time stays ~90us,
// the scattered-access throughput wall is confirmed (next: (rel,dst) sort).
template <int K>
__global__ __launch_bounds__(256, 8)
void edge_gemm_kernel(const _Float16* __restrict__ hin, const _Float16* __restrict__ Wt,
                      const int* __restrict__ esrc, const int* __restrict__ eq,
                      const float* __restrict__ escale,
                      const int* __restrict__ tile_rel, const int* __restrict__ tile_start,
                      const int* __restrict__ tile_nrows,
                      _Float16* __restrict__ Y) {
    int bid = blockIdx.x;
    int rh  = (bid >= MAXT) ? 1 : 0;          // row half: rows [rh*32, rh*32+32)
    int t   = bid - rh * MAXT;
    // Balanced relation-local XCD swizzle (bijective: 9*384 = 3456).
    int x = t & 7, i = t >> 3;
    int c = i / 48, j = i % 48;
    int tile = c * 384 + x * 48 + j;

    int nr = tile_nrows[tile];
    int r0 = rh * 32;
    if (nr <= r0) return;
    int nloc = min(32, nr - r0);              // rows this block handles
    int rel  = tile_rel[tile];
    int ts   = tile_start[tile] + r0;         // local row lr -> edge ts+lr

    constexpr int KH  = (K > 128) ? 128 : K;  // staged K per pass
    constexpr int LK  = KH + 8;               // A stride (fp16)
    constexpr int SO  = HDIM + 8;             // out stride = 264
    constexpr int AEL = 32 * LK;
    constexpr int OEL = 32 * SO;
    constexpr int EL  = (AEL > OEL) ? AEL : OEL;   // 8448
    __shared__ _Float16 sbuf[EL];             // A tile, then reused for out tile
    __shared__ int   sq[32];
    __shared__ float sscale[32];

    int tid = threadIdx.x;
    if (tid < 32) {
        if (tid < nloc) { sq[tid] = eq[ts + tid]; sscale[tid] = escale[ts + tid]; }
        else            { sq[tid] = 0;            sscale[tid] = 0.f; }
    }

    int lane = tid & 63, w = tid >> 6;
    int lm = lane & 15, quad = lane >> 4;
    f32x4 acc[2][4] = {};
    // wave w owns cols [w*64, w*64+64)
    const _Float16* Bbase = Wt + ((size_t)rel * HDIM + w * 64 + lm) * K + quad * 8;
    const _Float16* Abase = sbuf + lm * LK + quad * 8;

    constexpr int CPR = KH / 8;               // 16B chunks per row per pass
    for (int kh = 0; kh < K; kh += KH) {
        for (int idx = tid; idx < 32 * CPR; idx += 256) {
            int row = idx / CPR, cc = idx % CPR;
            u32x4 v = {0, 0, 0, 0};
            if (row < nloc) {
                int src = esrc[ts + row];
                v = *(const u32x4*)(hin + (size_t)src * K + kh + cc * 8);
            }
            *(u32x4*)&sbuf[row * LK + cc * 8] = v;
        }
        __syncthreads();

        for (int kk = 0; kk < KH; kk += 32) {
            half8 a0 = *(const half8*)(Abase + kk);
            half8 a1 = *(const half8*)(Abase + 16 * LK + kk);
            #pragma unroll
            for (int nt = 0; nt < 4; nt++) {
                half8 b = *(const half8*)(Bbase + nt * 16 * K + kh + kk);
                acc[0][nt] = __builtin_amdgcn_mfma_f32_16x16x32_f16(a0, b, acc[0][nt], 0, 0, 0);
                acc[1][nt] = __builtin_amdgcn_mfma_f32_16x16x32_f16(a1, b, acc[1][nt], 0, 0, 0);
            }
        }
        __syncthreads();   // A reads done before restage / epilogue reuse
    }

    // Epilogue through LDS (sbuf reused as [32][264] out tile).
    // D[m][n]: m = mt*16 + quad*4 + rr (local row), n = w*64 + nt*16 + lm
    #pragma unroll
    for (int mt = 0; mt < 2; mt++) {
        #pragma unroll
        for (int rr = 0; rr < 4; rr++) {
            int row = mt * 16 + quad * 4 + rr;
            float s = sscale[row];
            #pragma unroll
            for (int nt = 0; nt < 4; nt++)
                sbuf[row * SO + w * 64 + nt * 16 + lm] = (_Float16)(acc[mt][nt][rr] * s);
        }
    }
    __syncthreads();
    // 32 rows x 512 B (full rows -> clean 256B-per-half writes): 1024 chunks
    for (int idx = tid; idx < 32 * 32; idx += 256) {
        int row = idx >> 5, seg = idx & 31;
        if (row < nloc) {
            u32x4 v = *(const u32x4*)&sbuf[row * SO + seg * 8];
            __builtin_nontemporal_store(v, (u32x4*)(Y + (size_t)sq[row] * HDIM + seg * 8));
        }
    }
}

// ---------------- phase 2: CSR segment-reduce + bias + relu -> h16 ----------------
// Wave-per-node, barrier-free. 2000 blocks x 4 waves.
__global__ __launch_bounds__(256)
void reduce_kernel(const _Float16* __restrict__ Y, const int* __restrict__ dst_off,
                   const float* __restrict__ bias, _Float16* __restrict__ hout) {
    int node = blockIdx.x * 4 + (threadIdx.x >> 6);
    int lane = threadIdx.x & 63;
    int start = dst_off[node], end = dst_off[node + 1];
    int c = lane & 31;       // col group: 8 fp16 -> 32 groups = 256 cols
    int r = lane >> 5;       // 2-way row split
    float acc[8] = {0, 0, 0, 0, 0, 0, 0, 0};
    for (int jj = start + r; jj < end; jj += 2) {
        u32x4 u = __builtin_nontemporal_load((const u32x4*)(Y + (size_t)jj * HDIM + c * 8));
        half8 v = *(half8*)&u;
        #pragma unroll
        for (int k = 0; k < 8; k++) acc[k] += (float)v[k];
    }
    #pragma unroll
    for (int k = 0; k < 8; k++) acc[k] += __shfl_down(acc[k], 32, 64);
    if (lane < 32) {
        half8 o;
        #pragma unroll
        for (int k = 0; k < 8; k++) {
            float v = acc[k] + bias[c * 8 + k];
            o[k] = (_Float16)(v > 0.f ? v : 0.f);
        }
        *(half8*)(hout + (size_t)node * HDIM + c * 8) = o;
    }
}

// ---------------- pooling + head (atomic-free) ----------------

// One wave per node: gate[n] = sigmoid(h[n] . ws_w + ws_b)
__global__ void gate_kernel(const _Float16* __restrict__ h, const float* __restrict__ ws_w,
                            const float* __restrict__ ws_b, float* __restrict__ gate) {
    int node = blockIdx.x * 4 + (threadIdx.x >> 6);
    int lane = threadIdx.x & 63;
    half4 v = *(const half4*)(h + (size_t)node * HDIM + lane * 4);
    float s = 0.f;
    #pragma unroll
    for (int k = 0; k < 4; k++) s += (float)v[k] * ws_w[lane * 4 + k];
    for (int o = 32; o > 0; o >>= 1) s += __shfl_down(s, o, 64);
    if (lane == 0) gate[node] = 1.f / (1.f + __expf(-(s + ws_b[0])));
}

// One block per graph; batch is sorted, so segments are contiguous (binary search).
__global__ void pool_kernel(const _Float16* __restrict__ h, const float* __restrict__ gate,
                            const int* __restrict__ batch, float* __restrict__ pooled) {
    int g = blockIdx.x, t = threadIdx.x;
    int a = 0, b = NNODES;
    while (a < b) { int m = (a + b) >> 1; if (batch[m] < g) a = m + 1; else b = m; }
    int lo = a;
    b = NNODES;
    while (a < b) { int m = (a + b) >> 1; if (batch[m] < g + 1) a = m + 1; else b = m; }
    int hi = a;
    float acc = 0.f;
    for (int n = lo; n < hi; n++)
        acc += gate[n] * (float)h[(size_t)n * HDIM + t];
    pooled[(size_t)g * HDIM + t] = acc;
}

__global__ void head_kernel(const float* __restrict__ pooled,
                            const float* __restrict__ w1, const float* __restrict__ b1,
                            const float* __restrict__ w2, const float* __restrict__ b2,
                            const float* __restrict__ w3, const float* __restrict__ b3,
                            float* __restrict__ out) {
    int b = blockIdx.x, tid = threadIdx.x;   // 64 threads = 1 wave
    __shared__ float sp[HDIM];
    __shared__ float m1[MDIM];
    __shared__ float m2[MDIM];
    for (int i = tid; i < HDIM; i += 64) sp[i] = pooled[(size_t)b * HDIM + i];
    __syncthreads();
    float a = b1[tid];
    for (int i = 0; i < HDIM; i++) a += sp[i] * w1[i * MDIM + tid];
    m1[tid] = a > 0.f ? a : 0.f;
    __syncthreads();
    float c = b2[tid];
    for (int i = 0; i < MDIM; i++) c += m1[i] * w2[i * MDIM + tid];
    m2[tid] = c > 0.f ? c : 0.f;
    __syncthreads();
    float p = m2[tid] * w3[tid];
    for (int o = 32; o > 0; o >>= 1) p += __shfl_down(p, o, 64);
    if (tid == 0) out[b] = p + b3[0];
}

// ---------------- launch ----------------

extern "C" void kernel_launch(void* const* d_in, const int* in_sizes, int n_in,
                              void* d_out, int out_size, void* d_ws, size_t ws_size,
                              hipStream_t stream) {
    const float* x     = (const float*)d_in[0];
    const int*   ei    = (const int*)d_in[1];
    const int*   et    = (const int*)d_in[2];
    const int*   batch = (const int*)d_in[3];
    const float* W1    = (const float*)d_in[4];
    const float* root1 = (const float*)d_in[5];
    const float* b1    = (const float*)d_in[6];
    const float* W2    = (const float*)d_in[7];
    const float* root2 = (const float*)d_in[8];
    const float* b2    = (const float*)d_in[9];
    const float* W3    = (const float*)d_in[10];
    const float* root3 = (const float*)d_in[11];
    const float* b3    = (const float*)d_in[12];
    const float* ws_w  = (const float*)d_in[13];
    const float* ws_b  = (const float*)d_in[14];
    const float* m_w1  = (const float*)d_in[15];
    const float* m_b1  = (const float*)d_in[16];
    const float* m_w2  = (const float*)d_in[17];
    const float* m_b2  = (const float*)d_in[18];
    const float* m_w3  = (const float*)d_in[19];
    const float* m_b3  = (const float*)d_in[20];
    float* out = (float*)d_out;

    char* ws = (char*)d_ws;
    size_t o = 0;
    auto take = [&](size_t bytes) { size_t r = o; o = (o + bytes + 255) & ~(size_t)255; return r; };

    size_t o_cnt_rn = take((size_t)NREL * NNODES * 4);
    size_t o_tcnt   = take(RP * 4);
    size_t o_tcur   = take(RP * 4);
    size_t o_toff   = take((RP + 1) * 4);
    size_t o_ddeg   = take((size_t)NNODES * 4);
    size_t o_dcur   = take((size_t)NNODES * 4);
    size_t o_doff   = take((size_t)(NNODES + 1) * 4);
    size_t o_esrc   = take((size_t)EPTOT * 4);
    size_t o_eq     = take((size_t)EPTOT * 4);
    size_t o_escale = take((size_t)EPTOT * 4);
    size_t o_trel   = take(MAXT * 4);
    size_t o_tstart = take(MAXT * 4);
    size_t o_tnrows = take(MAXT * 4);
    size_t o_wt1    = take((size_t)RP * HDIM * FDIM * 2);
    size_t o_wt2    = take((size_t)RP * HDIM * HDIM * 2);
    size_t o_wt3    = take((size_t)RP * HDIM * HDIM * 2);
    size_t o_x16    = take((size_t)NNODES * FDIM * 2);
    size_t o_h16    = take((size_t)NNODES * HDIM * 2);
    size_t o_gate   = take((size_t)NNODES * 4);
    size_t o_pool   = take((size_t)NGRAPH * HDIM * 4);
    size_t o_y16    = take((size_t)EPTOT * HDIM * 2);   // 102.4 MB

    int*      cnt_rn   = (int*)(ws + o_cnt_rn);
    int*      type_cnt = (int*)(ws + o_tcnt);
    int*      type_cur = (int*)(ws + o_tcur);
    int*      type_off = (int*)(ws + o_toff);
    int*      ddeg     = (int*)(ws + o_ddeg);
    int*      dst_cur  = (int*)(ws + o_dcur);
    int*      dst_off  = (int*)(ws + o_doff);
    int*      esrc     = (int*)(ws + o_esrc);
    int*      eq       = (int*)(ws + o_eq);
    float*    escale   = (float*)(ws + o_escale);
    int*      trel     = (int*)(ws + o_trel);
    int*      tstart   = (int*)(ws + o_tstart);
    int*      tnrows   = (int*)(ws + o_tnrows);
    _Float16* Wt1      = (_Float16*)(ws + o_wt1);
    _Float16* Wt2      = (_Float16*)(ws + o_wt2);
    _Float16* Wt3      = (_Float16*)(ws + o_wt3);
    _Float16* x16      = (_Float16*)(ws + o_x16);
    _Float16* h16      = (_Float16*)(ws + o_h16);
    float*    gate     = (float*)(ws + o_gate);
    float*    pooled   = (float*)(ws + o_pool);
    _Float16* Y16      = (_Float16*)(ws + o_y16);

    // zero: cnt_rn + type_cnt + type_cur (contiguous); ddeg + dst_cur (contiguous); tile_nrows
    hipMemsetAsync(ws + o_cnt_rn, 0, o_toff - o_cnt_rn, stream);
    hipMemsetAsync(ws + o_ddeg, 0, o_doff - o_ddeg, stream);
    hipMemsetAsync(ws + o_tnrows, 0, MAXT * 4, stream);

    count_kernel<<<(NEDGES + 255) / 256, 256, 0, stream>>>(ei, et, cnt_rn, type_cnt, ddeg);
    scan_tiles_kernel<<<1, 128, 0, stream>>>(type_cnt, type_off, trel, tstart, tnrows);
    dst_scan_kernel<<<1, 256, 0, stream>>>(ddeg, dst_off);
    scatter_kernel<<<(EPTOT + 255) / 256, 256, 0, stream>>>(ei, et, cnt_rn, type_off, type_cur,
                                                            dst_off, dst_cur, esrc, eq, escale);

    convW_kernel<<<dim3(RP, FDIM / 32, HDIM / 32), 256, 0, stream>>>(W1, root1, Wt1, FDIM);
    convW_kernel<<<dim3(RP, HDIM / 32, HDIM / 32), 256, 0, stream>>>(W2, root2, Wt2, HDIM);
    convW_kernel<<<dim3(RP, HDIM / 32, HDIM / 32), 256, 0, stream>>>(W3, root3, Wt3, HDIM);
    conv_x_kernel<<<(NNODES * FDIM + 255) / 256, 256, 0, stream>>>(x, x16);

    // Layer 1 (K=64)
    edge_gemm_kernel<FDIM><<<2 * MAXT, 256, 0, stream>>>(x16, Wt1, esrc, eq, escale,
                                                         trel, tstart, tnrows, Y16);
    reduce_kernel<<<NNODES / 4, 256, 0, stream>>>(Y16, dst_off, b1, h16);

    // Layer 2 (K=256)
    edge_gemm_kernel<HDIM><<<2 * MAXT, 256, 0, stream>>>(h16, Wt2, esrc, eq, escale,
                                                         trel, tstart, tnrows, Y16);
    reduce_kernel<<<NNODES / 4, 256, 0, stream>>>(Y16, dst_off, b2, h16);

    // Layer 3 (K=256)
    edge_gemm_kernel<HDIM><<<2 * MAXT, 256, 0, stream>>>(h16, Wt3, esrc, eq, escale,
                                                         trel, tstart, tnrows, Y16);
    reduce_kernel<<<NNODES / 4, 256, 0, stream>>>(Y16, dst_off, b3, h16);

    gate_kernel<<<NNODES / 4, 256, 0, stream>>>(h16, ws_w, ws_b, gate);
    pool_kernel<<<NGRAPH, 256, 0, stream>>>(h16, gate, batch, pooled);
    head_kernel<<<NGRAPH, 64, 0, stream>>>(pooled, m_w1, m_b1, m_w2, m_b2, m_w3, m_b3, out);

    (void)in_sizes; (void)n_in; (void)out_size; (void)ws_size;
}

// Round 8
// 564.972 us; speedup vs baseline: 1.0550x; 1.0550x over previous
//
#include <hip/hip_runtime.h>

// Problem constants (fixed by setup_inputs)
#define NNODES 8000
#define NEDGES 192000
#define NREL   65
#define RP     66      // +1 pseudo-relation for the root/self term
#define HDIM   256
#define FDIM   64
#define NGRAPH 128
#define MDIM   64
#define TILE_M 64
#define MAXT   3456    // >= E/64 + RP + N/64 = 3190; == 8*432; pairs: 1728 == 9*192
#define NPAIR  (MAXT / 2)
#define EPTOT  (NEDGES + NNODES)

typedef _Float16 half8 __attribute__((ext_vector_type(8)));
typedef _Float16 half4 __attribute__((ext_vector_type(4)));
typedef float    f32x4 __attribute__((ext_vector_type(4)));
// clang vector type (NOT HIP's struct uint4) — required by __builtin_nontemporal_*
typedef unsigned int u32x4 __attribute__((ext_vector_type(4)));

// ---------------- setup kernels ----------------

__global__ void count_kernel(const int* __restrict__ ei, const int* __restrict__ et,
                             int* __restrict__ cnt_rn, int* __restrict__ type_cnt,
                             int* __restrict__ ddeg) {
    __shared__ int lbin[NREL];
    int tid = threadIdx.x;
    if (tid < NREL) lbin[tid] = 0;
    __syncthreads();
    int e = blockIdx.x * 256 + tid;
    if (e < NEDGES) {
        int t = et[e];
        int d = ei[NEDGES + e];
        atomicAdd(&lbin[t], 1);
        atomicAdd(&cnt_rn[t * NNODES + d], 1);
        atomicAdd(&ddeg[d], 1);
    }
    __syncthreads();
    if (tid < NREL && lbin[tid] > 0) atomicAdd(&type_cnt[tid], lbin[tid]);
}

__global__ void scan_tiles_kernel(const int* __restrict__ type_cnt, int* __restrict__ type_off,
                                  int* __restrict__ tile_rel, int* __restrict__ tile_start,
                                  int* __restrict__ tile_nrows) {
    __shared__ int s_off[RP + 1];
    __shared__ int s_toff[RP + 1];
    if (threadIdx.x == 0) {
        int off = 0, toff = 0;
        for (int r = 0; r < RP; r++) {
            int c = (r < NREL) ? type_cnt[r] : NNODES;
            s_off[r] = off; s_toff[r] = toff;
            off += c; toff += (c + TILE_M - 1) / TILE_M;
        }
        s_off[RP] = off; s_toff[RP] = toff;
        type_off[RP] = off;
    }
    __syncthreads();
    int r = threadIdx.x;
    if (r < RP) {
        type_off[r] = s_off[r];
        int c = s_off[r + 1] - s_off[r];
        int nt = (c + TILE_M - 1) / TILE_M;
        for (int i = 0; i < nt; i++) {
            int idx = s_toff[r] + i;
            tile_rel[idx]   = r;
            tile_start[idx] = s_off[r] + i * TILE_M;
            tile_nrows[idx] = min(TILE_M, c - i * TILE_M);
        }
    }
}

// Exclusive prefix scan of (ddeg[n]+1) -> dst_off[0..NNODES]; +1 = root pseudo-edge.
__global__ void dst_scan_kernel(const int* __restrict__ ddeg, int* __restrict__ dst_off) {
    __shared__ int part[256];
    int t = threadIdx.x;
    int base = t * 32;
    int s = 0;
    for (int i = 0; i < 32; i++) {
        int n = base + i;
        if (n < NNODES) s += ddeg[n] + 1;
    }
    part[t] = s;
    __syncthreads();
    if (t == 0) {
        int run = 0;
        for (int i = 0; i < 256; i++) { int tmp = part[i]; part[i] = run; run += tmp; }
        dst_off[NNODES] = run;   // == EPTOT
    }
    __syncthreads();
    int run = part[t];
    for (int i = 0; i < 32; i++) {
        int n = base + i;
        if (n < NNODES) { dst_off[n] = run; run += ddeg[n] + 1; }
    }
}

// Relation-sorted slot p (block-aggregated rank) + dst-sorted output slot q.
__global__ void scatter_kernel(const int* __restrict__ ei, const int* __restrict__ et,
                               const int* __restrict__ cnt_rn, const int* __restrict__ type_off,
                               int* __restrict__ type_cur,
                               const int* __restrict__ dst_off, int* __restrict__ dst_cur,
                               int* __restrict__ esrc, int* __restrict__ eq,
                               float* __restrict__ escale) {
    __shared__ int lbin[NREL];
    __shared__ int gbase[NREL];
    int tid = threadIdx.x;
    if (tid < NREL) lbin[tid] = 0;
    __syncthreads();
    int i = blockIdx.x * 256 + tid;
    int t = 0, lrank = 0;
    bool is_edge = (i < NEDGES);
    if (is_edge) {
        t = et[i];
        lrank = atomicAdd(&lbin[t], 1);
    }
    __syncthreads();
    if (tid < NREL && lbin[tid] > 0) gbase[tid] = atomicAdd(&type_cur[tid], lbin[tid]);
    __syncthreads();
    if (is_edge) {
        int d = ei[NEDGES + i];
        int p = type_off[t] + gbase[t] + lrank;
        int q = dst_off[d] + atomicAdd(&dst_cur[d], 1);
        esrc[p] = ei[i];
        eq[p] = q;
        escale[p] = 1.0f / (float)cnt_rn[t * NNODES + d];
    } else if (i < EPTOT) {
        int n = i - NEDGES;
        int p = NEDGES + n;      // root pseudo-relation segment starts at E
        int q = dst_off[n] + atomicAdd(&dst_cur[n], 1);
        esrc[p] = n; eq[p] = q; escale[p] = 1.0f;
    }
}

// W [R][K][HDIM] fp32 (+ root [K][HDIM]) -> Wt [RP][HDIM][K] fp16 (transposed)
__global__ void convW_kernel(const float* __restrict__ W, const float* __restrict__ root,
                             _Float16* __restrict__ Wt, int K) {
    int r = blockIdx.x, k0 = blockIdx.y * 32, n0 = blockIdx.z * 32;
    const float* src = (r < NREL) ? (W + (size_t)r * K * HDIM) : root;
    __shared__ float tile[32][33];
    int tj = threadIdx.x & 31, ti = threadIdx.x >> 5;
    #pragma unroll
    for (int s = 0; s < 4; s++) {
        int i = ti + s * 8;
        tile[i][tj] = src[(size_t)(k0 + i) * HDIM + n0 + tj];
    }
    __syncthreads();
    #pragma unroll
    for (int s = 0; s < 4; s++) {
        int i = ti + s * 8;
        Wt[((size_t)r * HDIM + (n0 + i)) * K + k0 + tj] = (_Float16)tile[tj][i];
    }
}

__global__ void conv_x_kernel(const float* __restrict__ x, _Float16* __restrict__ x16) {
    int i = blockIdx.x * 256 + threadIdx.x;
    if (i < NNODES * FDIM) x16[i] = (_Float16)x[i];
}

// ---------------- phase 1: Y16[q] = scale * (h[src] @ W_r) ----------------
// Round 8: T14 async-stage pipeline on the PROVEN R0 tile (64x256, 4 waves).
// R3/R6/R7 post-mortems: occupancy 26->73% bought nothing; every tile split
// ADDED traffic and time. Shared flaw of all variants: the random A-gather
// (~900 cyc) sits fully exposed between stage->vmcnt(0)->barrier->MFMA.
// Fix (plain HIP, T14 recipe): 2 tiles per block; each unit's gather is
// issued into REGISTERS before the previous unit's MFMA phase, ds_written
// to LDS only after the barrier. Gather latency hides under MFMA+epilogue.
// Separate epilogue buffer lets tile0's stores overlap tile1's compute.
template <int K>
__global__ __launch_bounds__(256, 3)
void edge_gemm_kernel(const _Float16* __restrict__ hin, const _Float16* __restrict__ Wt,
                      const int* __restrict__ esrc, const int* __restrict__ eq,
                      const float* __restrict__ escale,
                      const int* __restrict__ tile_rel, const int* __restrict__ tile_start,
                      const int* __restrict__ tile_nrows,
                      _Float16* __restrict__ Y) {
    constexpr int KH   = (K > 128) ? 128 : K;   // staged K per unit
    constexpr int LK   = KH + 8;                // A stride (fp16), +8 pad
    constexpr int SO   = HDIM + 8;              // out stride = 264
    constexpr int CPR  = KH / 8;                // 16B chunks per row
    constexpr int CPT  = (TILE_M * CPR) / 256;  // chunks per thread (4 or 2)
    constexpr int RSTEP = 256 / CPR;            // row stride between a thread's chunks

    __shared__ _Float16 abuf[TILE_M * LK];      // A staging buffer
    __shared__ _Float16 obuf[TILE_M * SO];      // epilogue transpose buffer

    // Balanced XCD swizzle on tile PAIRS (bijective: 1728 = 9*192).
    int p = blockIdx.x;
    int x = p & 7, ii = p >> 3;
    int pc = ii / 24, pj = ii % 24;
    int pair = pc * 192 + x * 24 + pj;
    int t0 = pair * 2, t1 = t0 + 1;

    int nr0 = tile_nrows[t0], nr1 = tile_nrows[t1];
    if ((nr0 | nr1) == 0) return;               // uniform per block
    int ts0 = tile_start[t0], ts1 = tile_start[t1];
    int rel0 = tile_rel[t0],  rel1 = tile_rel[t1];

    int tid = threadIdx.x;
    int lane = tid & 63, w = tid >> 6;
    int lm = lane & 15, quad = lane >> 4;

    int ch   = tid % CPR;                       // chunk-in-row (fixed per thread)
    int row0 = tid / CPR;

    u32x4 sreg[CPT];                            // in-flight staging registers
    f32x4 acc[4][4] = {};

    auto LOADR = [&](int nr, int ts, int kh) {  // issue gather -> regs (async)
        #pragma unroll
        for (int q = 0; q < CPT; q++) {
            int row = row0 + q * RSTEP;
            u32x4 v = {0, 0, 0, 0};
            if (row < nr) {
                int src = esrc[ts + row];
                v = *(const u32x4*)(hin + (size_t)src * K + kh + ch * 8);
            }
            sreg[q] = v;
        }
    };
    auto DSW = [&]() {                          // regs -> LDS (waits vmcnt on sreg)
        #pragma unroll
        for (int q = 0; q < CPT; q++) {
            int row = row0 + q * RSTEP;
            *(u32x4*)&abuf[row * LK + ch * 8] = sreg[q];
        }
    };
    auto MFMA = [&](int rel, int kh) {
        const _Float16* Bb = Wt + ((size_t)rel * HDIM + w * 64 + lm) * K + kh + quad * 8;
        const _Float16* Ab = abuf + lm * LK + quad * 8;
        for (int kk = 0; kk < KH; kk += 32) {
            half8 a[4], b[4];
            #pragma unroll
            for (int mt = 0; mt < 4; mt++) a[mt] = *(const half8*)(Ab + mt * 16 * LK + kk);
            #pragma unroll
            for (int nt = 0; nt < 4; nt++) b[nt] = *(const half8*)(Bb + (size_t)nt * 16 * K + kk);
            #pragma unroll
            for (int mt = 0; mt < 4; mt++)
                #pragma unroll
                for (int nt = 0; nt < 4; nt++)
                    acc[mt][nt] = __builtin_amdgcn_mfma_f32_16x16x32_f16(a[mt], b[nt], acc[mt][nt], 0, 0, 0);
        }
    };
    auto EPI_LDS = [&](int nr, int ts) {        // acc -> obuf (scaled fp16)
        #pragma unroll
        for (int mt = 0; mt < 4; mt++) {
            #pragma unroll
            for (int rr = 0; rr < 4; rr++) {
                int row = mt * 16 + quad * 4 + rr;
                float s = (row < nr) ? escale[ts + row] : 0.f;
                #pragma unroll
                for (int nt = 0; nt < 4; nt++)
                    obuf[row * SO + w * 64 + nt * 16 + lm] = (_Float16)(acc[mt][nt][rr] * s);
            }
        }
    };
    auto EPI_STORE = [&](int nr, int ts) {      // obuf -> Y (vectorized NT rows)
        for (int idx = tid; idx < TILE_M * 32; idx += 256) {
            int row = idx >> 5, seg = idx & 31;
            if (row < nr) {
                int qq = eq[ts + row];
                u32x4 v = *(const u32x4*)&obuf[row * SO + seg * 8];
                __builtin_nontemporal_store(v, (u32x4*)(Y + (size_t)qq * HDIM + seg * 8));
            }
        }
    };
    auto ZACC = [&]() {
        #pragma unroll
        for (int mt = 0; mt < 4; mt++)
            #pragma unroll
            for (int nt = 0; nt < 4; nt++)
                acc[mt][nt] = f32x4{0.f, 0.f, 0.f, 0.f};
    };

    if constexpr (K > 128) {
        // Units: (t0,0) (t0,KH) (t1,0) (t1,KH)
        LOADR(nr0, ts0, 0);  DSW();  __syncthreads();   // prologue (latency exposed once)
        LOADR(nr0, ts0, KH);                            // in flight under MFMA
        MFMA(rel0, 0);
        __syncthreads();                                // abuf reads done
        DSW();  __syncthreads();                        // abuf <- (t0,KH)
        LOADR(nr1, ts1, 0);                             // in flight under MFMA+epilogue
        MFMA(rel0, KH);                                 // acc(t0) complete
        EPI_LDS(nr0, ts0);                              // obuf (no abuf conflict)
        __syncthreads();                                // abuf reads done + obuf visible
        EPI_STORE(nr0, ts0);                            // NT stores drain in background
        DSW();                                          // abuf <- (t1,0)
        __syncthreads();
        ZACC();
        LOADR(nr1, ts1, KH);
        MFMA(rel1, 0);
        __syncthreads();
        DSW();  __syncthreads();
        MFMA(rel1, KH);
        EPI_LDS(nr1, ts1);
        __syncthreads();
        EPI_STORE(nr1, ts1);
    } else {
        // Units: (t0) (t1), single KH pass each
        LOADR(nr0, ts0, 0);  DSW();  __syncthreads();
        LOADR(nr1, ts1, 0);                             // in flight under MFMA+epilogue
        MFMA(rel0, 0);
        EPI_LDS(nr0, ts0);
        __syncthreads();
        EPI_STORE(nr0, ts0);
        DSW();
        __syncthreads();
        ZACC();
        MFMA(rel1, 0);
        EPI_LDS(nr1, ts1);
        __syncthreads();
        EPI_STORE(nr1, ts1);
    }
}

// ---------------- phase 2: CSR segment-reduce + bias + relu -> h16 ----------------
// Wave-per-node, barrier-free. 2000 blocks x 4 waves; CSR segments contiguous.
__global__ __launch_bounds__(256)
void reduce_kernel(const _Float16* __restrict__ Y, const int* __restrict__ dst_off,
                   const float* __restrict__ bias, _Float16* __restrict__ hout) {
    int node = blockIdx.x * 4 + (threadIdx.x >> 6);
    int lane = threadIdx.x & 63;
    int start = dst_off[node], end = dst_off[node + 1];
    int c = lane & 31;       // col group: 8 fp16 -> 32 groups = 256 cols
    int r = lane >> 5;       // 2-way row split
    float acc[8] = {0, 0, 0, 0, 0, 0, 0, 0};
    for (int jj = start + r; jj < end; jj += 2) {
        u32x4 u = __builtin_nontemporal_load((const u32x4*)(Y + (size_t)jj * HDIM + c * 8));
        half8 v = *(half8*)&u;
        #pragma unroll
        for (int k = 0; k < 8; k++) acc[k] += (float)v[k];
    }
    #pragma unroll
    for (int k = 0; k < 8; k++) acc[k] += __shfl_down(acc[k], 32, 64);
    if (lane < 32) {
        half8 o;
        #pragma unroll
        for (int k = 0; k < 8; k++) {
            float v = acc[k] + bias[c * 8 + k];
            o[k] = (_Float16)(v > 0.f ? v : 0.f);
        }
        *(half8*)(hout + (size_t)node * HDIM + c * 8) = o;
    }
}

// ---------------- pooling + head (atomic-free) ----------------

// One wave per node: gate[n] = sigmoid(h[n] . ws_w + ws_b)
__global__ void gate_kernel(const _Float16* __restrict__ h, const float* __restrict__ ws_w,
                            const float* __restrict__ ws_b, float* __restrict__ gate) {
    int node = blockIdx.x * 4 + (threadIdx.x >> 6);
    int lane = threadIdx.x & 63;
    half4 v = *(const half4*)(h + (size_t)node * HDIM + lane * 4);
    float s = 0.f;
    #pragma unroll
    for (int k = 0; k < 4; k++) s += (float)v[k] * ws_w[lane * 4 + k];
    for (int o = 32; o > 0; o >>= 1) s += __shfl_down(s, o, 64);
    if (lane == 0) gate[node] = 1.f / (1.f + __expf(-(s + ws_b[0])));
}

// One block per graph; batch is sorted, so segments are contiguous (binary search).
__global__ void pool_kernel(const _Float16* __restrict__ h, const float* __restrict__ gate,
                            const int* __restrict__ batch, float* __restrict__ pooled) {
    int g = blockIdx.x, t = threadIdx.x;
    int a = 0, b = NNODES;
    while (a < b) { int m = (a + b) >> 1; if (batch[m] < g) a = m + 1; else b = m; }
    int lo = a;
    b = NNODES;
    while (a < b) { int m = (a + b) >> 1; if (batch[m] < g + 1) a = m + 1; else b = m; }
    int hi = a;
    float acc = 0.f;
    for (int n = lo; n < hi; n++)
        acc += gate[n] * (float)h[(size_t)n * HDIM + t];
    pooled[(size_t)g * HDIM + t] = acc;
}

__global__ void head_kernel(const float* __restrict__ pooled,
                            const float* __restrict__ w1, const float* __restrict__ b1,
                            const float* __restrict__ w2, const float* __restrict__ b2,
                            const float* __restrict__ w3, const float* __restrict__ b3,
                            float* __restrict__ out) {
    int b = blockIdx.x, tid = threadIdx.x;   // 64 threads = 1 wave
    __shared__ float sp[HDIM];
    __shared__ float m1[MDIM];
    __shared__ float m2[MDIM];
    for (int i = tid; i < HDIM; i += 64) sp[i] = pooled[(size_t)b * HDIM + i];
    __syncthreads();
    float a = b1[tid];
    for (int i = 0; i < HDIM; i++) a += sp[i] * w1[i * MDIM + tid];
    m1[tid] = a > 0.f ? a : 0.f;
    __syncthreads();
    float c = b2[tid];
    for (int i = 0; i < MDIM; i++) c += m1[i] * w2[i * MDIM + tid];
    m2[tid] = c > 0.f ? c : 0.f;
    __syncthreads();
    float p = m2[tid] * w3[tid];
    for (int o = 32; o > 0; o >>= 1) p += __shfl_down(p, o, 64);
    if (tid == 0) out[b] = p + b3[0];
}

// ---------------- launch ----------------

extern "C" void kernel_launch(void* const* d_in, const int* in_sizes, int n_in,
                              void* d_out, int out_size, void* d_ws, size_t ws_size,
                              hipStream_t stream) {
    const float* x     = (const float*)d_in[0];
    const int*   ei    = (const int*)d_in[1];
    const int*   et    = (const int*)d_in[2];
    const int*   batch = (const int*)d_in[3];
    const float* W1    = (const float*)d_in[4];
    const float* root1 = (const float*)d_in[5];
    const float* b1    = (const float*)d_in[6];
    const float* W2    = (const float*)d_in[7];
    const float* root2 = (const float*)d_in[8];
    const float* b2    = (const float*)d_in[9];
    const float* W3    = (const float*)d_in[10];
    const float* root3 = (const float*)d_in[11];
    const float* b3    = (const float*)d_in[12];
    const float* ws_w  = (const float*)d_in[13];
    const float* ws_b  = (const float*)d_in[14];
    const float* m_w1  = (const float*)d_in[15];
    const float* m_b1  = (const float*)d_in[16];
    const float* m_w2  = (const float*)d_in[17];
    const float* m_b2  = (const float*)d_in[18];
    const float* m_w3  = (const float*)d_in[19];
    const float* m_b3  = (const float*)d_in[20];
    float* out = (float*)d_out;

    char* ws = (char*)d_ws;
    size_t o = 0;
    auto take = [&](size_t bytes) { size_t r = o; o = (o + bytes + 255) & ~(size_t)255; return r; };

    size_t o_cnt_rn = take((size_t)NREL * NNODES * 4);
    size_t o_tcnt   = take(RP * 4);
    size_t o_tcur   = take(RP * 4);
    size_t o_toff   = take((RP + 1) * 4);
    size_t o_ddeg   = take((size_t)NNODES * 4);
    size_t o_dcur   = take((size_t)NNODES * 4);
    size_t o_doff   = take((size_t)(NNODES + 1) * 4);
    size_t o_esrc   = take((size_t)EPTOT * 4);
    size_t o_eq     = take((size_t)EPTOT * 4);
    size_t o_escale = take((size_t)EPTOT * 4);
    size_t o_trel   = take(MAXT * 4);
    size_t o_tstart = take(MAXT * 4);
    size_t o_tnrows = take(MAXT * 4);
    size_t o_wt1    = take((size_t)RP * HDIM * FDIM * 2);
    size_t o_wt2    = take((size_t)RP * HDIM * HDIM * 2);
    size_t o_wt3    = take((size_t)RP * HDIM * HDIM * 2);
    size_t o_x16    = take((size_t)NNODES * FDIM * 2);
    size_t o_h16    = take((size_t)NNODES * HDIM * 2);
    size_t o_gate   = take((size_t)NNODES * 4);
    size_t o_pool   = take((size_t)NGRAPH * HDIM * 4);
    size_t o_y16    = take((size_t)EPTOT * HDIM * 2);   // 102.4 MB

    int*      cnt_rn   = (int*)(ws + o_cnt_rn);
    int*      type_cnt = (int*)(ws + o_tcnt);
    int*      type_cur = (int*)(ws + o_tcur);
    int*      type_off = (int*)(ws + o_toff);
    int*      ddeg     = (int*)(ws + o_ddeg);
    int*      dst_cur  = (int*)(ws + o_dcur);
    int*      dst_off  = (int*)(ws + o_doff);
    int*      esrc     = (int*)(ws + o_esrc);
    int*      eq       = (int*)(ws + o_eq);
    float*    escale   = (float*)(ws + o_escale);
    int*      trel     = (int*)(ws + o_trel);
    int*      tstart   = (int*)(ws + o_tstart);
    int*      tnrows   = (int*)(ws + o_tnrows);
    _Float16* Wt1      = (_Float16*)(ws + o_wt1);
    _Float16* Wt2      = (_Float16*)(ws + o_wt2);
    _Float16* Wt3      = (_Float16*)(ws + o_wt3);
    _Float16* x16      = (_Float16*)(ws + o_x16);
    _Float16* h16      = (_Float16*)(ws + o_h16);
    float*    gate     = (float*)(ws + o_gate);
    float*    pooled   = (float*)(ws + o_pool);
    _Float16* Y16      = (_Float16*)(ws + o_y16);

    // zero: cnt_rn + type_cnt + type_cur (contiguous); ddeg + dst_cur (contiguous); tile_nrows
    hipMemsetAsync(ws + o_cnt_rn, 0, o_toff - o_cnt_rn, stream);
    hipMemsetAsync(ws + o_ddeg, 0, o_doff - o_ddeg, stream);
    hipMemsetAsync(ws + o_tnrows, 0, MAXT * 4, stream);

    count_kernel<<<(NEDGES + 255) / 256, 256, 0, stream>>>(ei, et, cnt_rn, type_cnt, ddeg);
    scan_tiles_kernel<<<1, 128, 0, stream>>>(type_cnt, type_off, trel, tstart, tnrows);
    dst_scan_kernel<<<1, 256, 0, stream>>>(ddeg, dst_off);
    scatter_kernel<<<(EPTOT + 255) / 256, 256, 0, stream>>>(ei, et, cnt_rn, type_off, type_cur,
                                                            dst_off, dst_cur, esrc, eq, escale);

    convW_kernel<<<dim3(RP, FDIM / 32, HDIM / 32), 256, 0, stream>>>(W1, root1, Wt1, FDIM);
    convW_kernel<<<dim3(RP, HDIM / 32, HDIM / 32), 256, 0, stream>>>(W2, root2, Wt2, HDIM);
    convW_kernel<<<dim3(RP, HDIM / 32, HDIM / 32), 256, 0, stream>>>(W3, root3, Wt3, HDIM);
    conv_x_kernel<<<(NNODES * FDIM + 255) / 256, 256, 0, stream>>>(x, x16);

    // Layer 1 (K=64)
    edge_gemm_kernel<FDIM><<<NPAIR, 256, 0, stream>>>(x16, Wt1, esrc, eq, escale,
                                                      trel, tstart, tnrows, Y16);
    reduce_kernel<<<NNODES / 4, 256, 0, stream>>>(Y16, dst_off, b1, h16);

    // Layer 2 (K=256)
    edge_gemm_kernel<HDIM><<<NPAIR, 256, 0, stream>>>(h16, Wt2, esrc, eq, escale,
                                                      trel, tstart, tnrows, Y16);
    reduce_kernel<<<NNODES / 4, 256, 0, stream>>>(Y16, dst_off, b2, h16);

    // Layer 3 (K=256)
    edge_gemm_kernel<HDIM><<<NPAIR, 256, 0, stream>>>(h16, Wt3, esrc, eq, escale,
                                                      trel, tstart, tnrows, Y16);
    reduce_kernel<<<NNODES / 4, 256, 0, stream>>>(Y16, dst_off, b3, h16);

    gate_kernel<<<NNODES / 4, 256, 0, stream>>>(h16, ws_w, ws_b, gate);
    pool_kernel<<<NGRAPH, 256, 0, stream>>>(h16, gate, batch, pooled);
    head_kernel<<<NGRAPH, 64, 0, stream>>>(pooled, m_w1, m_b1, m_w2, m_b2, m_w3, m_b3, out);

    (void)in_sizes; (void)n_in; (void)out_size; (void)ws_size;
}

// Round 9
// 482.962 us; speedup vs baseline: 1.2342x; 1.1698x over previous
//
#include <hip/hip_runtime.h>

// Problem constants (fixed by setup_inputs)
#define NNODES 8000
#define NEDGES 192000
#define NREL   65
#define RP     66      // +1 pseudo-relation for the root/self term
#define HDIM   256
#define FDIM   64
#define NGRAPH 128
#define MDIM   64
#define TILE_M 64
#define MAXT   3456    // >= E/64 + RP + N/64 = 3190; == 8*432 for XCD swizzle
#define EPTOT  (NEDGES + NNODES)

typedef _Float16 half8 __attribute__((ext_vector_type(8)));
typedef _Float16 half4 __attribute__((ext_vector_type(4)));
typedef float    f32x4 __attribute__((ext_vector_type(4)));
// clang vector type (NOT HIP's struct uint4) — required by __builtin_nontemporal_*
typedef unsigned int u32x4 __attribute__((ext_vector_type(4)));

// ---------------- setup kernels ----------------

__global__ void count_kernel(const int* __restrict__ ei, const int* __restrict__ et,
                             int* __restrict__ cnt_rn, int* __restrict__ type_cnt,
                             int* __restrict__ ddeg) {
    __shared__ int lbin[NREL];
    int tid = threadIdx.x;
    if (tid < NREL) lbin[tid] = 0;
    __syncthreads();
    int e = blockIdx.x * 256 + tid;
    if (e < NEDGES) {
        int t = et[e];
        int d = ei[NEDGES + e];
        atomicAdd(&lbin[t], 1);
        atomicAdd(&cnt_rn[t * NNODES + d], 1);
        atomicAdd(&ddeg[d], 1);
    }
    __syncthreads();
    if (tid < NREL && lbin[tid] > 0) atomicAdd(&type_cnt[tid], lbin[tid]);
}

__global__ void scan_tiles_kernel(const int* __restrict__ type_cnt, int* __restrict__ type_off,
                                  int* __restrict__ tile_rel, int* __restrict__ tile_start,
                                  int* __restrict__ tile_nrows) {
    __shared__ int s_off[RP + 1];
    __shared__ int s_toff[RP + 1];
    if (threadIdx.x == 0) {
        int off = 0, toff = 0;
        for (int r = 0; r < RP; r++) {
            int c = (r < NREL) ? type_cnt[r] : NNODES;
            s_off[r] = off; s_toff[r] = toff;
            off += c; toff += (c + TILE_M - 1) / TILE_M;
        }
        s_off[RP] = off; s_toff[RP] = toff;
        type_off[RP] = off;
    }
    __syncthreads();
    int r = threadIdx.x;
    if (r < RP) {
        type_off[r] = s_off[r];
        int c = s_off[r + 1] - s_off[r];
        int nt = (c + TILE_M - 1) / TILE_M;
        for (int i = 0; i < nt; i++) {
            int idx = s_toff[r] + i;
            tile_rel[idx]   = r;
            tile_start[idx] = s_off[r] + i * TILE_M;
            tile_nrows[idx] = min(TILE_M, c - i * TILE_M);
        }
    }
}

// Exclusive prefix scan of (ddeg[n]+1) -> dst_off[0..NNODES]; +1 = root pseudo-edge.
__global__ void dst_scan_kernel(const int* __restrict__ ddeg, int* __restrict__ dst_off) {
    __shared__ int part[256];
    int t = threadIdx.x;
    int base = t * 32;
    int s = 0;
    for (int i = 0; i < 32; i++) {
        int n = base + i;
        if (n < NNODES) s += ddeg[n] + 1;
    }
    part[t] = s;
    __syncthreads();
    if (t == 0) {
        int run = 0;
        for (int i = 0; i < 256; i++) { int tmp = part[i]; part[i] = run; run += tmp; }
        dst_off[NNODES] = run;   // == EPTOT
    }
    __syncthreads();
    int run = part[t];
    for (int i = 0; i < 32; i++) {
        int n = base + i;
        if (n < NNODES) { dst_off[n] = run; run += ddeg[n] + 1; }
    }
}

// Relation-sorted slot p (block-aggregated rank) + dst-sorted output slot q.
__global__ void scatter_kernel(const int* __restrict__ ei, const int* __restrict__ et,
                               const int* __restrict__ cnt_rn, const int* __restrict__ type_off,
                               int* __restrict__ type_cur,
                               const int* __restrict__ dst_off, int* __restrict__ dst_cur,
                               int* __restrict__ esrc, int* __restrict__ eq,
                               float* __restrict__ escale) {
    __shared__ int lbin[NREL];
    __shared__ int gbase[NREL];
    int tid = threadIdx.x;
    if (tid < NREL) lbin[tid] = 0;
    __syncthreads();
    int i = blockIdx.x * 256 + tid;
    int t = 0, lrank = 0;
    bool is_edge = (i < NEDGES);
    if (is_edge) {
        t = et[i];
        lrank = atomicAdd(&lbin[t], 1);
    }
    __syncthreads();
    if (tid < NREL && lbin[tid] > 0) gbase[tid] = atomicAdd(&type_cur[tid], lbin[tid]);
    __syncthreads();
    if (is_edge) {
        int d = ei[NEDGES + i];
        int p = type_off[t] + gbase[t] + lrank;
        int q = dst_off[d] + atomicAdd(&dst_cur[d], 1);
        esrc[p] = ei[i];
        eq[p] = q;
        escale[p] = 1.0f / (float)cnt_rn[t * NNODES + d];
    } else if (i < EPTOT) {
        int n = i - NEDGES;
        int p = NEDGES + n;      // root pseudo-relation segment starts at E
        int q = dst_off[n] + atomicAdd(&dst_cur[n], 1);
        esrc[p] = n; eq[p] = q; escale[p] = 1.0f;
    }
}

// W [R][K][HDIM] fp32 (+ root [K][HDIM]) -> Wt [RP][HDIM][K] fp16 (transposed)
__global__ void convW_kernel(const float* __restrict__ W, const float* __restrict__ root,
                             _Float16* __restrict__ Wt, int K) {
    int r = blockIdx.x, k0 = blockIdx.y * 32, n0 = blockIdx.z * 32;
    const float* src = (r < NREL) ? (W + (size_t)r * K * HDIM) : root;
    __shared__ float tile[32][33];
    int tj = threadIdx.x & 31, ti = threadIdx.x >> 5;
    #pragma unroll
    for (int s = 0; s < 4; s++) {
        int i = ti + s * 8;
        tile[i][tj] = src[(size_t)(k0 + i) * HDIM + n0 + tj];
    }
    __syncthreads();
    #pragma unroll
    for (int s = 0; s < 4; s++) {
        int i = ti + s * 8;
        Wt[((size_t)r * HDIM + (n0 + i)) * K + k0 + tj] = (_Float16)tile[tj][i];
    }
}

__global__ void conv_x_kernel(const float* __restrict__ x, _Float16* __restrict__ x16) {
    int i = blockIdx.x * 256 + threadIdx.x;
    if (i < NNODES * FDIM) x16[i] = (_Float16)x[i];
}

// ---------------- phase 1: Y16[q] = scale * (h[src] @ W_r) ----------------
// Round 9: R0 skeleton (best: 86.7us) + the one untried documented lever:
// __builtin_amdgcn_global_load_lds width=16 for A staging (guide CM#1:
// +67% isolated; compiler never auto-emits). Removes the VGPR round-trip
// (2048 per-thread load+ds_write pairs -> 32 wave-level DMA insts/block).
// gload_lds needs a LINEAR LDS dest (m104) -> no pad; bank conflicts on the
// A ds_read fixed via m173's pattern: pre-swizzle the per-lane GLOBAL source
// chunk (c ^= row&7) and apply the same XOR on the read side (involution).
// Keeps: R3's XCD swizzle (FETCH 71.7->25.7 proven), NT Y-stores, 3 barriers.
template <int K>
__global__ __launch_bounds__(256)
void edge_gemm_kernel(const _Float16* __restrict__ hin, const _Float16* __restrict__ Wt,
                      const int* __restrict__ esrc, const int* __restrict__ eq,
                      const float* __restrict__ escale,
                      const int* __restrict__ tile_rel, const int* __restrict__ tile_start,
                      const int* __restrict__ tile_nrows,
                      _Float16* __restrict__ Y) {
    // XCD swizzle: relation-sorted tiles colocate per XCD. Bijective: 8*432.
    int bid  = blockIdx.x;
    int tile = (bid & 7) * (MAXT / 8) + (bid >> 3);

    int nr = tile_nrows[tile];
    if (nr == 0) return;
    int r  = tile_rel[tile];
    int ts = tile_start[tile];

    constexpr int SO  = HDIM + 8;              // out stride (fp16) = 264
    constexpr int AEL = TILE_M * K;            // UNPADDED A tile (linear for DMA)
    constexpr int OEL = TILE_M * SO;
    constexpr int EL  = (AEL > OEL) ? AEL : OEL;
    __shared__ _Float16 sbuf[EL];              // A tile, then reused for out tile
    __shared__ int   sq[TILE_M];
    __shared__ float sscale[TILE_M];

    int tid = threadIdx.x;
    int lane = tid & 63, w = tid >> 6;
    int lm = lane & 15, quad = lane >> 4;

    // ---- async staging: global -> LDS DMA, pre-swizzled source ----
    // chunk ci = global 16B-chunk index; LDS slot ci holds global chunk
    // (row, cidx ^ (row&7)). IPW wave-insts of 1KB each (64 lanes x 16B).
    constexpr int CPR = K / 8;                 // 16B chunks per row (32 / 8)
    constexpr int IPW = (TILE_M * CPR) / 256;  // insts per wave (8 / 2)
    int rl = lane / CPR;                       // row offset within inst
    int cs = lane % CPR;                       // lane's LDS chunk slot within row
    #pragma unroll
    for (int i = 0; i < IPW; i++) {
        int rr  = (w * IPW + i) * (64 / CPR) + rl;
        int src = esrc[ts + ((rr < nr) ? rr : 0)];
        int c   = cs ^ (rr & 7);               // pre-swizzled source chunk
        const _Float16* gp = hin + (size_t)src * K + c * 8;
        _Float16* lp = sbuf + (w * IPW + i) * 512;   // wave-uniform base (1KB)
        __builtin_amdgcn_global_load_lds(
            (const __attribute__((address_space(1))) void*)gp,
            (__attribute__((address_space(3))) void*)lp,
            16, 0, 0);
    }
    if (tid < TILE_M) {
        if (tid < nr) { sq[tid] = eq[ts + tid]; sscale[tid] = escale[ts + tid]; }
        else          { sq[tid] = 0;            sscale[tid] = 0.f; }
    }
    __syncthreads();   // drains vmcnt (DMA complete) + barrier

    f32x4 acc[4][4] = {};
    const _Float16* Bbase = Wt + ((size_t)r * HDIM + w * 64 + lm) * K + quad * 8;
    int axor = lm & 7;

    for (int kk = 0; kk < K; kk += 32) {
        half8 a[4], b[4];
        int cidx = (((kk >> 3) + quad) ^ axor) * 8;   // swizzled read offset
        #pragma unroll
        for (int mt = 0; mt < 4; mt++)
            a[mt] = *(const half8*)(sbuf + (mt * 16 + lm) * K + cidx);
        #pragma unroll
        for (int nt = 0; nt < 4; nt++)
            b[nt] = *(const half8*)(Bbase + nt * 16 * K + kk);
        #pragma unroll
        for (int mt = 0; mt < 4; mt++)
            #pragma unroll
            for (int nt = 0; nt < 4; nt++)
                acc[mt][nt] = __builtin_amdgcn_mfma_f32_16x16x32_f16(a[mt], b[nt], acc[mt][nt], 0, 0, 0);
    }

    __syncthreads();   // all A reads complete before reuse as out tile

    // Epilogue through LDS (sbuf reused as [64][264] out tile).
    // D[m][n]: m = mt*16 + quad*4 + rr, n = w*64 + nt*16 + lm
    #pragma unroll
    for (int mt = 0; mt < 4; mt++) {
        #pragma unroll
        for (int rr = 0; rr < 4; rr++) {
            int row = mt * 16 + quad * 4 + rr;
            float s = sscale[row];
            #pragma unroll
            for (int nt = 0; nt < 4; nt++)
                sbuf[row * SO + w * 64 + nt * 16 + lm] = (_Float16)(acc[mt][nt][rr] * s);
        }
    }
    __syncthreads();

    // 64 rows x 512 B, vectorized NT: 2048 16B chunks over 256 threads
    for (int idx = tid; idx < TILE_M * 32; idx += 256) {
        int row = idx >> 5, seg = idx & 31;
        if (row < nr) {
            u32x4 v = *(const u32x4*)&sbuf[row * SO + seg * 8];
            __builtin_nontemporal_store(v, (u32x4*)(Y + (size_t)sq[row] * HDIM + seg * 8));
        }
    }
}

// ---------------- phase 2: CSR segment-reduce + bias + relu -> h16 ----------------
// Wave-per-node, barrier-free. 2000 blocks x 4 waves.
__global__ __launch_bounds__(256)
void reduce_kernel(const _Float16* __restrict__ Y, const int* __restrict__ dst_off,
                   const float* __restrict__ bias, _Float16* __restrict__ hout) {
    int node = blockIdx.x * 4 + (threadIdx.x >> 6);
    int lane = threadIdx.x & 63;
    int start = dst_off[node], end = dst_off[node + 1];
    int c = lane & 31;       // col group: 8 fp16 -> 32 groups = 256 cols
    int r = lane >> 5;       // 2-way row split
    float acc[8] = {0, 0, 0, 0, 0, 0, 0, 0};
    for (int jj = start + r; jj < end; jj += 2) {
        u32x4 u = __builtin_nontemporal_load((const u32x4*)(Y + (size_t)jj * HDIM + c * 8));
        half8 v = *(half8*)&u;
        #pragma unroll
        for (int k = 0; k < 8; k++) acc[k] += (float)v[k];
    }
    #pragma unroll
    for (int k = 0; k < 8; k++) acc[k] += __shfl_down(acc[k], 32, 64);
    if (lane < 32) {
        half8 o;
        #pragma unroll
        for (int k = 0; k < 8; k++) {
            float v = acc[k] + bias[c * 8 + k];
            o[k] = (_Float16)(v > 0.f ? v : 0.f);
        }
        *(half8*)(hout + (size_t)node * HDIM + c * 8) = o;
    }
}

// ---------------- pooling + head (atomic-free) ----------------

// One wave per node: gate[n] = sigmoid(h[n] . ws_w + ws_b)
__global__ void gate_kernel(const _Float16* __restrict__ h, const float* __restrict__ ws_w,
                            const float* __restrict__ ws_b, float* __restrict__ gate) {
    int node = blockIdx.x * 4 + (threadIdx.x >> 6);
    int lane = threadIdx.x & 63;
    half4 v = *(const half4*)(h + (size_t)node * HDIM + lane * 4);
    float s = 0.f;
    #pragma unroll
    for (int k = 0; k < 4; k++) s += (float)v[k] * ws_w[lane * 4 + k];
    for (int o = 32; o > 0; o >>= 1) s += __shfl_down(s, o, 64);
    if (lane == 0) gate[node] = 1.f / (1.f + __expf(-(s + ws_b[0])));
}

// One block per graph; batch is sorted, so segments are contiguous (binary search).
__global__ void pool_kernel(const _Float16* __restrict__ h, const float* __restrict__ gate,
                            const int* __restrict__ batch, float* __restrict__ pooled) {
    int g = blockIdx.x, t = threadIdx.x;
    int a = 0, b = NNODES;
    while (a < b) { int m = (a + b) >> 1; if (batch[m] < g) a = m + 1; else b = m; }
    int lo = a;
    b = NNODES;
    while (a < b) { int m = (a + b) >> 1; if (batch[m] < g + 1) a = m + 1; else b = m; }
    int hi = a;
    float acc = 0.f;
    for (int n = lo; n < hi; n++)
        acc += gate[n] * (float)h[(size_t)n * HDIM + t];
    pooled[(size_t)g * HDIM + t] = acc;
}

__global__ void head_kernel(const float* __restrict__ pooled,
                            const float* __restrict__ w1, const float* __restrict__ b1,
                            const float* __restrict__ w2, const float* __restrict__ b2,
                            const float* __restrict__ w3, const float* __restrict__ b3,
                            float* __restrict__ out) {
    int b = blockIdx.x, tid = threadIdx.x;   // 64 threads = 1 wave
    __shared__ float sp[HDIM];
    __shared__ float m1[MDIM];
    __shared__ float m2[MDIM];
    for (int i = tid; i < HDIM; i += 64) sp[i] = pooled[(size_t)b * HDIM + i];
    __syncthreads();
    float a = b1[tid];
    for (int i = 0; i < HDIM; i++) a += sp[i] * w1[i * MDIM + tid];
    m1[tid] = a > 0.f ? a : 0.f;
    __syncthreads();
    float c = b2[tid];
    for (int i = 0; i < MDIM; i++) c += m1[i] * w2[i * MDIM + tid];
    m2[tid] = c > 0.f ? c : 0.f;
    __syncthreads();
    float p = m2[tid] * w3[tid];
    for (int o = 32; o > 0; o >>= 1) p += __shfl_down(p, o, 64);
    if (tid == 0) out[b] = p + b3[0];
}

// ---------------- launch ----------------

extern "C" void kernel_launch(void* const* d_in, const int* in_sizes, int n_in,
                              void* d_out, int out_size, void* d_ws, size_t ws_size,
                              hipStream_t stream) {
    const float* x     = (const float*)d_in[0];
    const int*   ei    = (const int*)d_in[1];
    const int*   et    = (const int*)d_in[2];
    const int*   batch = (const int*)d_in[3];
    const float* W1    = (const float*)d_in[4];
    const float* root1 = (const float*)d_in[5];
    const float* b1    = (const float*)d_in[6];
    const float* W2    = (const float*)d_in[7];
    const float* root2 = (const float*)d_in[8];
    const float* b2    = (const float*)d_in[9];
    const float* W3    = (const float*)d_in[10];
    const float* root3 = (const float*)d_in[11];
    const float* b3    = (const float*)d_in[12];
    const float* ws_w  = (const float*)d_in[13];
    const float* ws_b  = (const float*)d_in[14];
    const float* m_w1  = (const float*)d_in[15];
    const float* m_b1  = (const float*)d_in[16];
    const float* m_w2  = (const float*)d_in[17];
    const float* m_b2  = (const float*)d_in[18];
    const float* m_w3  = (const float*)d_in[19];
    const float* m_b3  = (const float*)d_in[20];
    float* out = (float*)d_out;

    char* ws = (char*)d_ws;
    size_t o = 0;
    auto take = [&](size_t bytes) { size_t r = o; o = (o + bytes + 255) & ~(size_t)255; return r; };

    size_t o_cnt_rn = take((size_t)NREL * NNODES * 4);
    size_t o_tcnt   = take(RP * 4);
    size_t o_tcur   = take(RP * 4);
    size_t o_toff   = take((RP + 1) * 4);
    size_t o_ddeg   = take((size_t)NNODES * 4);
    size_t o_dcur   = take((size_t)NNODES * 4);
    size_t o_doff   = take((size_t)(NNODES + 1) * 4);
    size_t o_esrc   = take((size_t)EPTOT * 4);
    size_t o_eq     = take((size_t)EPTOT * 4);
    size_t o_escale = take((size_t)EPTOT * 4);
    size_t o_trel   = take(MAXT * 4);
    size_t o_tstart = take(MAXT * 4);
    size_t o_tnrows = take(MAXT * 4);
    size_t o_wt1    = take((size_t)RP * HDIM * FDIM * 2);
    size_t o_wt2    = take((size_t)RP * HDIM * HDIM * 2);
    size_t o_wt3    = take((size_t)RP * HDIM * HDIM * 2);
    size_t o_x16    = take((size_t)NNODES * FDIM * 2);
    size_t o_h16    = take((size_t)NNODES * HDIM * 2);
    size_t o_gate   = take((size_t)NNODES * 4);
    size_t o_pool   = take((size_t)NGRAPH * HDIM * 4);
    size_t o_y16    = take((size_t)EPTOT * HDIM * 2);   // 102.4 MB

    int*      cnt_rn   = (int*)(ws + o_cnt_rn);
    int*      type_cnt = (int*)(ws + o_tcnt);
    int*      type_cur = (int*)(ws + o_tcur);
    int*      type_off = (int*)(ws + o_toff);
    int*      ddeg     = (int*)(ws + o_ddeg);
    int*      dst_cur  = (int*)(ws + o_dcur);
    int*      dst_off  = (int*)(ws + o_doff);
    int*      esrc     = (int*)(ws + o_esrc);
    int*      eq       = (int*)(ws + o_eq);
    float*    escale   = (float*)(ws + o_escale);
    int*      trel     = (int*)(ws + o_trel);
    int*      tstart   = (int*)(ws + o_tstart);
    int*      tnrows   = (int*)(ws + o_tnrows);
    _Float16* Wt1      = (_Float16*)(ws + o_wt1);
    _Float16* Wt2      = (_Float16*)(ws + o_wt2);
    _Float16* Wt3      = (_Float16*)(ws + o_wt3);
    _Float16* x16      = (_Float16*)(ws + o_x16);
    _Float16* h16      = (_Float16*)(ws + o_h16);
    float*    gate     = (float*)(ws + o_gate);
    float*    pooled   = (float*)(ws + o_pool);
    _Float16* Y16      = (_Float16*)(ws + o_y16);

    // zero: cnt_rn + type_cnt + type_cur (contiguous); ddeg + dst_cur (contiguous); tile_nrows
    hipMemsetAsync(ws + o_cnt_rn, 0, o_toff - o_cnt_rn, stream);
    hipMemsetAsync(ws + o_ddeg, 0, o_doff - o_ddeg, stream);
    hipMemsetAsync(ws + o_tnrows, 0, MAXT * 4, stream);

    count_kernel<<<(NEDGES + 255) / 256, 256, 0, stream>>>(ei, et, cnt_rn, type_cnt, ddeg);
    scan_tiles_kernel<<<1, 128, 0, stream>>>(type_cnt, type_off, trel, tstart, tnrows);
    dst_scan_kernel<<<1, 256, 0, stream>>>(ddeg, dst_off);
    scatter_kernel<<<(EPTOT + 255) / 256, 256, 0, stream>>>(ei, et, cnt_rn, type_off, type_cur,
                                                            dst_off, dst_cur, esrc, eq, escale);

    convW_kernel<<<dim3(RP, FDIM / 32, HDIM / 32), 256, 0, stream>>>(W1, root1, Wt1, FDIM);
    convW_kernel<<<dim3(RP, HDIM / 32, HDIM / 32), 256, 0, stream>>>(W2, root2, Wt2, HDIM);
    convW_kernel<<<dim3(RP, HDIM / 32, HDIM / 32), 256, 0, stream>>>(W3, root3, Wt3, HDIM);
    conv_x_kernel<<<(NNODES * FDIM + 255) / 256, 256, 0, stream>>>(x, x16);

    // Layer 1 (K=64)
    edge_gemm_kernel<FDIM><<<MAXT, 256, 0, stream>>>(x16, Wt1, esrc, eq, escale,
                                                     trel, tstart, tnrows, Y16);
    reduce_kernel<<<NNODES / 4, 256, 0, stream>>>(Y16, dst_off, b1, h16);

    // Layer 2 (K=256)
    edge_gemm_kernel<HDIM><<<MAXT, 256, 0, stream>>>(h16, Wt2, esrc, eq, escale,
                                                     trel, tstart, tnrows, Y16);
    reduce_kernel<<<NNODES / 4, 256, 0, stream>>>(Y16, dst_off, b2, h16);

    // Layer 3 (K=256)
    edge_gemm_kernel<HDIM><<<MAXT, 256, 0, stream>>>(h16, Wt3, esrc, eq, escale,
                                                     trel, tstart, tnrows, Y16);
    reduce_kernel<<<NNODES / 4, 256, 0, stream>>>(Y16, dst_off, b3, h16);

    gate_kernel<<<NNODES / 4, 256, 0, stream>>>(h16, ws_w, ws_b, gate);
    pool_kernel<<<NGRAPH, 256, 0, stream>>>(h16, gate, batch, pooled);
    head_kernel<<<NGRAPH, 64, 0, stream>>>(pooled, m_w1, m_b1, m_w2, m_b2, m_w3, m_b3, out);

    (void)in_sizes; (void)n_in; (void)out_size; (void)ws_size;
}

// Round 11
// 456.583 us; speedup vs baseline: 1.3055x; 1.0578x over previous
//
#include <hip/hip_runtime.h>

// Problem constants (fixed by setup_inputs)
#define NNODES 8000
#define NEDGES 192000
#define NREL   65
#define RP     66      // +1 pseudo-relation for the root/self term
#define HDIM   256
#define FDIM   64
#define NGRAPH 128
#define MDIM   64
#define TILE_M 128
#define MAXT   1664    // >= sum ceil(c_r/128) <= 1565 + 63 = 1628; == 8*208 for swizzle
#define EPTOT  (NEDGES + NNODES)

typedef _Float16 half8 __attribute__((ext_vector_type(8)));
typedef _Float16 half4 __attribute__((ext_vector_type(4)));
typedef float    f32x4 __attribute__((ext_vector_type(4)));
// clang vector type (NOT HIP's struct uint4) — required by __builtin_nontemporal_*
typedef unsigned int u32x4 __attribute__((ext_vector_type(4)));

// ---------------- setup kernels ----------------

__global__ void count_kernel(const int* __restrict__ ei, const int* __restrict__ et,
                             int* __restrict__ cnt_rn, int* __restrict__ type_cnt,
                             int* __restrict__ ddeg) {
    __shared__ int lbin[NREL];
    int tid = threadIdx.x;
    if (tid < NREL) lbin[tid] = 0;
    __syncthreads();
    int e = blockIdx.x * 256 + tid;
    if (e < NEDGES) {
        int t = et[e];
        int d = ei[NEDGES + e];
        atomicAdd(&lbin[t], 1);
        atomicAdd(&cnt_rn[t * NNODES + d], 1);
        atomicAdd(&ddeg[d], 1);
    }
    __syncthreads();
    if (tid < NREL && lbin[tid] > 0) atomicAdd(&type_cnt[tid], lbin[tid]);
}

__global__ void scan_tiles_kernel(const int* __restrict__ type_cnt, int* __restrict__ type_off,
                                  int* __restrict__ tile_rel, int* __restrict__ tile_start,
                                  int* __restrict__ tile_nrows) {
    __shared__ int s_off[RP + 1];
    __shared__ int s_toff[RP + 1];
    if (threadIdx.x == 0) {
        int off = 0, toff = 0;
        for (int r = 0; r < RP; r++) {
            int c = (r < NREL) ? type_cnt[r] : NNODES;
            s_off[r] = off; s_toff[r] = toff;
            off += c; toff += (c + TILE_M - 1) / TILE_M;
        }
        s_off[RP] = off; s_toff[RP] = toff;
        type_off[RP] = off;
    }
    __syncthreads();
    int r = threadIdx.x;
    if (r < RP) {
        type_off[r] = s_off[r];
        int c = s_off[r + 1] - s_off[r];
        int nt = (c + TILE_M - 1) / TILE_M;
        for (int i = 0; i < nt; i++) {
            int idx = s_toff[r] + i;
            tile_rel[idx]   = r;
            tile_start[idx] = s_off[r] + i * TILE_M;
            tile_nrows[idx] = min(TILE_M, c - i * TILE_M);
        }
    }
}

// Exclusive prefix scan of (ddeg[n]+1) -> dst_off[0..NNODES]; +1 = root pseudo-edge.
__global__ void dst_scan_kernel(const int* __restrict__ ddeg, int* __restrict__ dst_off) {
    __shared__ int part[256];
    int t = threadIdx.x;
    int base = t * 32;
    int s = 0;
    for (int i = 0; i < 32; i++) {
        int n = base + i;
        if (n < NNODES) s += ddeg[n] + 1;
    }
    part[t] = s;
    __syncthreads();
    if (t == 0) {
        int run = 0;
        for (int i = 0; i < 256; i++) { int tmp = part[i]; part[i] = run; run += tmp; }
        dst_off[NNODES] = run;   // == EPTOT
    }
    __syncthreads();
    int run = part[t];
    for (int i = 0; i < 32; i++) {
        int n = base + i;
        if (n < NNODES) { dst_off[n] = run; run += ddeg[n] + 1; }
    }
}

// Relation-sorted slot p (block-aggregated rank) + dst-sorted output slot q.
__global__ void scatter_kernel(const int* __restrict__ ei, const int* __restrict__ et,
                               const int* __restrict__ cnt_rn, const int* __restrict__ type_off,
                               int* __restrict__ type_cur,
                               const int* __restrict__ dst_off, int* __restrict__ dst_cur,
                               int* __restrict__ esrc, int* __restrict__ eq,
                               float* __restrict__ escale) {
    __shared__ int lbin[NREL];
    __shared__ int gbase[NREL];
    int tid = threadIdx.x;
    if (tid < NREL) lbin[tid] = 0;
    __syncthreads();
    int i = blockIdx.x * 256 + tid;
    int t = 0, lrank = 0;
    bool is_edge = (i < NEDGES);
    if (is_edge) {
        t = et[i];
        lrank = atomicAdd(&lbin[t], 1);
    }
    __syncthreads();
    if (tid < NREL && lbin[tid] > 0) gbase[tid] = atomicAdd(&type_cur[tid], lbin[tid]);
    __syncthreads();
    if (is_edge) {
        int d = ei[NEDGES + i];
        int p = type_off[t] + gbase[t] + lrank;
        int q = dst_off[d] + atomicAdd(&dst_cur[d], 1);
        esrc[p] = ei[i];
        eq[p] = q;
        escale[p] = 1.0f / (float)cnt_rn[t * NNODES + d];
    } else if (i < EPTOT) {
        int n = i - NEDGES;
        int p = NEDGES + n;      // root pseudo-relation segment starts at E
        int q = dst_off[n] + atomicAdd(&dst_cur[n], 1);
        esrc[p] = n; eq[p] = q; escale[p] = 1.0f;
    }
}

// W [R][K][HDIM] fp32 (+ root [K][HDIM]) -> Wt [RP][HDIM][K] fp16 (transposed)
__global__ void convW_kernel(const float* __restrict__ W, const float* __restrict__ root,
                             _Float16* __restrict__ Wt, int K) {
    int r = blockIdx.x, k0 = blockIdx.y * 32, n0 = blockIdx.z * 32;
    const float* src = (r < NREL) ? (W + (size_t)r * K * HDIM) : root;
    __shared__ float tile[32][33];
    int tj = threadIdx.x & 31, ti = threadIdx.x >> 5;
    #pragma unroll
    for (int s = 0; s < 4; s++) {
        int i = ti + s * 8;
        tile[i][tj] = src[(size_t)(k0 + i) * HDIM + n0 + tj];
    }
    __syncthreads();
    #pragma unroll
    for (int s = 0; s < 4; s++) {
        int i = ti + s * 8;
        Wt[((size_t)r * HDIM + (n0 + i)) * K + k0 + tj] = (_Float16)tile[tj][i];
    }
}

__global__ void conv_x_kernel(const float* __restrict__ x, _Float16* __restrict__ x16) {
    int i = blockIdx.x * 256 + threadIdx.x;
    if (i < NNODES * FDIM) x16[i] = (_Float16)x[i];
}

// ---------------- phase 1: Y16[q] = scale * (h[src] @ W_r) ----------------
// Round 11: TILE_M=128 (R10 intent) with the R10 LDS-overflow bug FIXED:
// sbuf must be sized max(A-tile, epilogue-tile). R10 sized it TILE_M*K only;
// for K=64 the [64][264] epilogue overran into sq[] -> wild Y stores -> abort.
// Theory unchanged: time tracks per-block vector-memory line requests
// (~0.2 lines/cyc/CU); B is 2/3 of them and is relation-shared. 128-row
// tiles amortize 2048 B-lines over 2x edges: 48 -> 32 lines/edge.
template <int K>
__global__ __launch_bounds__(256)
void edge_gemm_kernel(const _Float16* __restrict__ hin, const _Float16* __restrict__ Wt,
                      const int* __restrict__ esrc, const int* __restrict__ eq,
                      const float* __restrict__ escale,
                      const int* __restrict__ tile_rel, const int* __restrict__ tile_start,
                      const int* __restrict__ tile_nrows,
                      _Float16* __restrict__ Y) {
    // XCD swizzle: relation-sorted tiles colocate per XCD. Bijective: 8*208.
    int bid  = blockIdx.x;
    int tile = (bid & 7) * (MAXT / 8) + (bid >> 3);

    int nr = tile_nrows[tile];
    if (nr == 0) return;
    int r  = tile_rel[tile];
    int ts = tile_start[tile];

    constexpr int SO  = HDIM + 8;              // epilogue out stride = 264
    constexpr int AEL = TILE_M * K;            // UNPADDED A tile (linear for DMA)
    constexpr int OEL = 64 * SO;               // 64-row epilogue half
    constexpr int EL  = (AEL > OEL) ? AEL : OEL;   // R10 bug fix: union sizing
    __shared__ _Float16 sbuf[EL];              // A tile, then reused for out halves
    __shared__ int   sq[TILE_M];
    __shared__ float sscale[TILE_M];

    int tid = threadIdx.x;
    int lane = tid & 63, w = tid >> 6;
    int lm = lane & 15, quad = lane >> 4;

    // ---- async staging: global -> LDS DMA, pre-swizzled source ----
    // LDS chunk slot (row, cs) holds global chunk (row, cs ^ (row&7)).
    constexpr int CPR = K / 8;                 // 16B chunks per row (32 / 8)
    constexpr int IPW = (TILE_M * CPR) / 256;  // DMA insts per wave (16 / 4)
    constexpr int RPI = 64 / CPR;              // rows covered per inst (2 / 8)
    int rl = lane / CPR;                       // row offset within inst
    int cs = lane % CPR;                       // lane's LDS chunk slot within row
    #pragma unroll
    for (int i = 0; i < IPW; i++) {
        int rr  = (w * IPW + i) * RPI + rl;
        int src = esrc[ts + ((rr < nr) ? rr : 0)];
        int c   = cs ^ (rr & 7);               // pre-swizzled source chunk
        const _Float16* gp = hin + (size_t)src * K + c * 8;
        _Float16* lp = sbuf + (w * IPW + i) * 512;   // wave-uniform base (1KB)
        __builtin_amdgcn_global_load_lds(
            (const __attribute__((address_space(1))) void*)gp,
            (__attribute__((address_space(3))) void*)lp,
            16, 0, 0);
    }
    if (tid < TILE_M) {
        if (tid < nr) { sq[tid] = eq[ts + tid]; sscale[tid] = escale[ts + tid]; }
        else          { sq[tid] = 0;            sscale[tid] = 0.f; }
    }
    __syncthreads();   // drains vmcnt (DMA complete) + barrier

    f32x4 acc[8][4] = {};
    const _Float16* Bbase = Wt + ((size_t)r * HDIM + w * 64 + lm) * K + quad * 8;
    int axor = lm & 7;

    for (int kk = 0; kk < K; kk += 32) {
        int cidx = (((kk >> 3) + quad) ^ axor) * 8;   // swizzled read offset
        half8 b[4];
        #pragma unroll
        for (int nt = 0; nt < 4; nt++)
            b[nt] = *(const half8*)(Bbase + nt * 16 * K + kk);
        #pragma unroll
        for (int mt = 0; mt < 8; mt++) {
            half8 a = *(const half8*)(sbuf + (mt * 16 + lm) * K + cidx);
            #pragma unroll
            for (int nt = 0; nt < 4; nt++)
                acc[mt][nt] = __builtin_amdgcn_mfma_f32_16x16x32_f16(a, b[nt], acc[mt][nt], 0, 0, 0);
        }
    }

    __syncthreads();   // all A reads complete before reuse as out tile

    // Epilogue in two 64-row halves through LDS (sbuf reused as [64][264]).
    // D[m][n]: m = mt*16 + quad*4 + rr, n = w*64 + nt*16 + lm
    #pragma unroll
    for (int h = 0; h < 2; h++) {
        #pragma unroll
        for (int ml = 0; ml < 4; ml++) {
            int mt = h * 4 + ml;
            #pragma unroll
            for (int rr = 0; rr < 4; rr++) {
                int lrow = ml * 16 + quad * 4 + rr;
                int row  = h * 64 + lrow;
                float s = sscale[row];
                #pragma unroll
                for (int nt = 0; nt < 4; nt++)
                    sbuf[lrow * SO + w * 64 + nt * 16 + lm] = (_Float16)(acc[mt][nt][rr] * s);
            }
        }
        __syncthreads();
        // 64 rows x 512 B, vectorized NT: 2048 16B chunks over 256 threads
        for (int idx = tid; idx < 64 * 32; idx += 256) {
            int lrow = idx >> 5, seg = idx & 31;
            int row  = h * 64 + lrow;
            if (row < nr) {
                u32x4 v = *(const u32x4*)&sbuf[lrow * SO + seg * 8];
                __builtin_nontemporal_store(v, (u32x4*)(Y + (size_t)sq[row] * HDIM + seg * 8));
            }
        }
        if (h == 0) __syncthreads();   // before half-1 reuses sbuf
    }
}

// ---------------- phase 2: CSR segment-reduce + bias + relu -> h16 ----------------
// Wave-per-node, barrier-free. 2000 blocks x 4 waves.
__global__ __launch_bounds__(256)
void reduce_kernel(const _Float16* __restrict__ Y, const int* __restrict__ dst_off,
                   const float* __restrict__ bias, _Float16* __restrict__ hout) {
    int node = blockIdx.x * 4 + (threadIdx.x >> 6);
    int lane = threadIdx.x & 63;
    int start = dst_off[node], end = dst_off[node + 1];
    int c = lane & 31;       // col group: 8 fp16 -> 32 groups = 256 cols
    int r = lane >> 5;       // 2-way row split
    float acc[8] = {0, 0, 0, 0, 0, 0, 0, 0};
    for (int jj = start + r; jj < end; jj += 2) {
        u32x4 u = __builtin_nontemporal_load((const u32x4*)(Y + (size_t)jj * HDIM + c * 8));
        half8 v = *(half8*)&u;
        #pragma unroll
        for (int k = 0; k < 8; k++) acc[k] += (float)v[k];
    }
    #pragma unroll
    for (int k = 0; k < 8; k++) acc[k] += __shfl_down(acc[k], 32, 64);
    if (lane < 32) {
        half8 o;
        #pragma unroll
        for (int k = 0; k < 8; k++) {
            float v = acc[k] + bias[c * 8 + k];
            o[k] = (_Float16)(v > 0.f ? v : 0.f);
        }
        *(half8*)(hout + (size_t)node * HDIM + c * 8) = o;
    }
}

// ---------------- pooling + head (atomic-free) ----------------

// One wave per node: gate[n] = sigmoid(h[n] . ws_w + ws_b)
__global__ void gate_kernel(const _Float16* __restrict__ h, const float* __restrict__ ws_w,
                            const float* __restrict__ ws_b, float* __restrict__ gate) {
    int node = blockIdx.x * 4 + (threadIdx.x >> 6);
    int lane = threadIdx.x & 63;
    half4 v = *(const half4*)(h + (size_t)node * HDIM + lane * 4);
    float s = 0.f;
    #pragma unroll
    for (int k = 0; k < 4; k++) s += (float)v[k] * ws_w[lane * 4 + k];
    for (int o = 32; o > 0; o >>= 1) s += __shfl_down(s, o, 64);
    if (lane == 0) gate[node] = 1.f / (1.f + __expf(-(s + ws_b[0])));
}

// One block per graph; batch is sorted, so segments are contiguous (binary search).
__global__ void pool_kernel(const _Float16* __restrict__ h, const float* __restrict__ gate,
                            const int* __restrict__ batch, float* __restrict__ pooled) {
    int g = blockIdx.x, t = threadIdx.x;
    int a = 0, b = NNODES;
    while (a < b) { int m = (a + b) >> 1; if (batch[m] < g) a = m + 1; else b = m; }
    int lo = a;
    b = NNODES;
    while (a < b) { int m = (a + b) >> 1; if (batch[m] < g + 1) a = m + 1; else b = m; }
    int hi = a;
    float acc = 0.f;
    for (int n = lo; n < hi; n++)
        acc += gate[n] * (float)h[(size_t)n * HDIM + t];
    pooled[(size_t)g * HDIM + t] = acc;
}

__global__ void head_kernel(const float* __restrict__ pooled,
                            const float* __restrict__ w1, const float* __restrict__ b1,
                            const float* __restrict__ w2, const float* __restrict__ b2,
                            const float* __restrict__ w3, const float* __restrict__ b3,
                            float* __restrict__ out) {
    int b = blockIdx.x, tid = threadIdx.x;   // 64 threads = 1 wave
    __shared__ float sp[HDIM];
    __shared__ float m1[MDIM];
    __shared__ float m2[MDIM];
    for (int i = tid; i < HDIM; i += 64) sp[i] = pooled[(size_t)b * HDIM + i];
    __syncthreads();
    float a = b1[tid];
    for (int i = 0; i < HDIM; i++) a += sp[i] * w1[i * MDIM + tid];
    m1[tid] = a > 0.f ? a : 0.f;
    __syncthreads();
    float c = b2[tid];
    for (int i = 0; i < MDIM; i++) c += m1[i] * w2[i * MDIM + tid];
    m2[tid] = c > 0.f ? c : 0.f;
    __syncthreads();
    float p = m2[tid] * w3[tid];
    for (int o = 32; o > 0; o >>= 1) p += __shfl_down(p, o, 64);
    if (tid == 0) out[b] = p + b3[0];
}

// ---------------- launch ----------------

extern "C" void kernel_launch(void* const* d_in, const int* in_sizes, int n_in,
                              void* d_out, int out_size, void* d_ws, size_t ws_size,
                              hipStream_t stream) {
    const float* x     = (const float*)d_in[0];
    const int*   ei    = (const int*)d_in[1];
    const int*   et    = (const int*)d_in[2];
    const int*   batch = (const int*)d_in[3];
    const float* W1    = (const float*)d_in[4];
    const float* root1 = (const float*)d_in[5];
    const float* b1    = (const float*)d_in[6];
    const float* W2    = (const float*)d_in[7];
    const float* root2 = (const float*)d_in[8];
    const float* b2    = (const float*)d_in[9];
    const float* W3    = (const float*)d_in[10];
    const float* root3 = (const float*)d_in[11];
    const float* b3    = (const float*)d_in[12];
    const float* ws_w  = (const float*)d_in[13];
    const float* ws_b  = (const float*)d_in[14];
    const float* m_w1  = (const float*)d_in[15];
    const float* m_b1  = (const float*)d_in[16];
    const float* m_w2  = (const float*)d_in[17];
    const float* m_b2  = (const float*)d_in[18];
    const float* m_w3  = (const float*)d_in[19];
    const float* m_b3  = (const float*)d_in[20];
    float* out = (float*)d_out;

    char* ws = (char*)d_ws;
    size_t o = 0;
    auto take = [&](size_t bytes) { size_t r = o; o = (o + bytes + 255) & ~(size_t)255; return r; };

    size_t o_cnt_rn = take((size_t)NREL * NNODES * 4);
    size_t o_tcnt   = take(RP * 4);
    size_t o_tcur   = take(RP * 4);
    size_t o_toff   = take((RP + 1) * 4);
    size_t o_ddeg   = take((size_t)NNODES * 4);
    size_t o_dcur   = take((size_t)NNODES * 4);
    size_t o_doff   = take((size_t)(NNODES + 1) * 4);
    size_t o_esrc   = take((size_t)EPTOT * 4);
    size_t o_eq     = take((size_t)EPTOT * 4);
    size_t o_escale = take((size_t)EPTOT * 4);
    size_t o_trel   = take(MAXT * 4);
    size_t o_tstart = take(MAXT * 4);
    size_t o_tnrows = take(MAXT * 4);
    size_t o_wt1    = take((size_t)RP * HDIM * FDIM * 2);
    size_t o_wt2    = take((size_t)RP * HDIM * HDIM * 2);
    size_t o_wt3    = take((size_t)RP * HDIM * HDIM * 2);
    size_t o_x16    = take((size_t)NNODES * FDIM * 2);
    size_t o_h16    = take((size_t)NNODES * HDIM * 2);
    size_t o_gate   = take((size_t)NNODES * 4);
    size_t o_pool   = take((size_t)NGRAPH * HDIM * 4);
    size_t o_y16    = take((size_t)EPTOT * HDIM * 2);   // 102.4 MB

    int*      cnt_rn   = (int*)(ws + o_cnt_rn);
    int*      type_cnt = (int*)(ws + o_tcnt);
    int*      type_cur = (int*)(ws + o_tcur);
    int*      type_off = (int*)(ws + o_toff);
    int*      ddeg     = (int*)(ws + o_ddeg);
    int*      dst_cur  = (int*)(ws + o_dcur);
    int*      dst_off  = (int*)(ws + o_doff);
    int*      esrc     = (int*)(ws + o_esrc);
    int*      eq       = (int*)(ws + o_eq);
    float*    escale   = (float*)(ws + o_escale);
    int*      trel     = (int*)(ws + o_trel);
    int*      tstart   = (int*)(ws + o_tstart);
    int*      tnrows   = (int*)(ws + o_tnrows);
    _Float16* Wt1      = (_Float16*)(ws + o_wt1);
    _Float16* Wt2      = (_Float16*)(ws + o_wt2);
    _Float16* Wt3      = (_Float16*)(ws + o_wt3);
    _Float16* x16      = (_Float16*)(ws + o_x16);
    _Float16* h16      = (_Float16*)(ws + o_h16);
    float*    gate     = (float*)(ws + o_gate);
    float*    pooled   = (float*)(ws + o_pool);
    _Float16* Y16      = (_Float16*)(ws + o_y16);

    // zero: cnt_rn + type_cnt + type_cur (contiguous); ddeg + dst_cur (contiguous); tile_nrows
    hipMemsetAsync(ws + o_cnt_rn, 0, o_toff - o_cnt_rn, stream);
    hipMemsetAsync(ws + o_ddeg, 0, o_doff - o_ddeg, stream);
    hipMemsetAsync(ws + o_tnrows, 0, MAXT * 4, stream);

    count_kernel<<<(NEDGES + 255) / 256, 256, 0, stream>>>(ei, et, cnt_rn, type_cnt, ddeg);
    scan_tiles_kernel<<<1, 128, 0, stream>>>(type_cnt, type_off, trel, tstart, tnrows);
    dst_scan_kernel<<<1, 256, 0, stream>>>(ddeg, dst_off);
    scatter_kernel<<<(EPTOT + 255) / 256, 256, 0, stream>>>(ei, et, cnt_rn, type_off, type_cur,
                                                            dst_off, dst_cur, esrc, eq, escale);

    convW_kernel<<<dim3(RP, FDIM / 32, HDIM / 32), 256, 0, stream>>>(W1, root1, Wt1, FDIM);
    convW_kernel<<<dim3(RP, HDIM / 32, HDIM / 32), 256, 0, stream>>>(W2, root2, Wt2, HDIM);
    convW_kernel<<<dim3(RP, HDIM / 32, HDIM / 32), 256, 0, stream>>>(W3, root3, Wt3, HDIM);
    conv_x_kernel<<<(NNODES * FDIM + 255) / 256, 256, 0, stream>>>(x, x16);

    // Layer 1 (K=64)
    edge_gemm_kernel<FDIM><<<MAXT, 256, 0, stream>>>(x16, Wt1, esrc, eq, escale,
                                                     trel, tstart, tnrows, Y16);
    reduce_kernel<<<NNODES / 4, 256, 0, stream>>>(Y16, dst_off, b1, h16);

    // Layer 2 (K=256)
    edge_gemm_kernel<HDIM><<<MAXT, 256, 0, stream>>>(h16, Wt2, esrc, eq, escale,
                                                     trel, tstart, tnrows, Y16);
    reduce_kernel<<<NNODES / 4, 256, 0, stream>>>(Y16, dst_off, b2, h16);

    // Layer 3 (K=256)
    edge_gemm_kernel<HDIM><<<MAXT, 256, 0, stream>>>(h16, Wt3, esrc, eq, escale,
                                                     trel, tstart, tnrows, Y16);
    reduce_kernel<<<NNODES / 4, 256, 0, stream>>>(Y16, dst_off, b3, h16);

    gate_kernel<<<NNODES / 4, 256, 0, stream>>>(h16, ws_w, ws_b, gate);
    pool_kernel<<<NGRAPH, 256, 0, stream>>>(h16, gate, batch, pooled);
    head_kernel<<<NGRAPH, 64, 0, stream>>>(pooled, m_w1, m_b1, m_w2, m_b2, m_w3, m_b3, out);

    (void)in_sizes; (void)n_in; (void)out_size; (void)ws_size;
}